// Round 7
// baseline (442.049 us; speedup 1.0000x reference)
//
#include <hip/hip_runtime.h>
#include <hip/hip_bf16.h>

#define N_NODES 50000
#define N_EDGES 800000
#define BROW 264   // padded LDS row stride in us (528 B = 33*16 -> b128-aligned, 2-way banks)

typedef __attribute__((ext_vector_type(8))) short bfrag8;   // 8 bf16 (4 VGPRs)
typedef __attribute__((ext_vector_type(4))) float f32x4;
typedef __attribute__((ext_vector_type(4))) unsigned short us4;
typedef __attribute__((ext_vector_type(8))) unsigned short us8;

__device__ __forceinline__ float bf2f(unsigned short u) {
  return __uint_as_float(((unsigned int)u) << 16);
}
__device__ __forceinline__ unsigned short f2bf(float f) {
  unsigned int u = __float_as_uint(f);
  u = (u + 0x7fffu + ((u >> 16) & 1u)) >> 16;
  return (unsigned short)u;
}
__device__ __forceinline__ float ldS(const void* p, int f32, size_t i) {
  return f32 ? ((const float*)p)[i] : bf2f(((const unsigned short*)p)[i]);
}
__device__ __forceinline__ void stO(void* out, int f32, int i, float v) {
  if (f32) ((float*)out)[i] = v;
  else ((unsigned short*)out)[i] = f2bf(v);
}

// Stage 64 rows x 256 cols of src (row indices nb..nb+63 clamped) into LDS,
// converting to bf16. 256 threads: thread t -> row t>>2, quarter t&3 (64 elems).
template <int F32>
__device__ __forceinline__ void stageB(const void* src, int nb,
                                       unsigned short* __restrict__ Bs) {
  const int t = threadIdx.x;
  const int r = t >> 2;
  const int q = t & 3;
  int row = nb + r;
  row = row < N_NODES ? row : (N_NODES - 1);
  const size_t base = (size_t)row * 256 + q * 64;
  unsigned short* dst = Bs + r * BROW + q * 64;
  if (F32) {
    const f32x4* s4 = (const f32x4*)((const float*)src + base);
#pragma unroll
    for (int j = 0; j < 8; ++j) {
      f32x4 a = s4[2 * j], b = s4[2 * j + 1];
      us8 o;
      o[0] = f2bf(a[0]); o[1] = f2bf(a[1]); o[2] = f2bf(a[2]); o[3] = f2bf(a[3]);
      o[4] = f2bf(b[0]); o[5] = f2bf(b[1]); o[6] = f2bf(b[2]); o[7] = f2bf(b[3]);
      *(us8*)(dst + j * 8) = o;
    }
  } else {
    const us8* s8 = (const us8*)((const unsigned short*)src + base);
#pragma unroll
    for (int j = 0; j < 8; ++j) *(us8*)(dst + j * 8) = s8[j];
  }
}

// flags: 0=x_is_f32 1=ea_is_f32 2=uf_is_f32 3=W_is_f32 4=idx_is_i64 5=out_is_f32
__global__ void k_detect(const void* x, const void* ea, const void* uf,
                         const void* f1W, const int* ei, int* flags) {
  int lane = threadIdx.x & 63;
  unsigned short ux = ((const unsigned short*)x)[lane];
  unsigned short ue = ((const unsigned short*)ea)[lane];
  unsigned short uu = ((const unsigned short*)uf)[lane];
  unsigned short uw = ((const unsigned short*)f1W)[lane];
  int oi = ei[2 * lane + 1];
  unsigned long long bx = __ballot(((ux >> 7) & 0xFF) > 0x85);
  unsigned long long be = __ballot((ue & 0x8000u) != 0);
  unsigned long long bu = __ballot(((uu >> 7) & 0xFF) > 0x85);
  unsigned long long bw = __ballot(((uw >> 7) & 0xFF) > 0x7E);
  unsigned long long bi = __ballot(oi != 0);
  if (lane == 0) {
    int fx = bx ? 1 : 0, fe = be ? 1 : 0, fu = bu ? 1 : 0, fw = bw ? 1 : 0;
    flags[0] = fx; flags[1] = fe; flags[2] = fu; flags[3] = fw;
    flags[4] = (bi == 0ull) ? 1 : 0;
    flags[5] = (fx & fe & fu & fw);
  }
}

// Normalize edges + zero counts/mlpc (one pass over 800k).
__global__ __launch_bounds__(256) void k_edges(const int* __restrict__ ei,
                                               const int* __restrict__ flags,
                                               int* __restrict__ srcW,
                                               int* __restrict__ dstW,
                                               int* __restrict__ cnt,
                                               float* __restrict__ mlpc) {
  int e = blockIdx.x * 256 + threadIdx.x;
  if (e >= N_EDGES) return;
  if (e <= N_NODES) cnt[e] = 0;
  if (e < N_NODES) mlpc[e] = 0.f;
  int i64 = flags[4];
  int s, d;
  if (i64) { s = ei[2 * e]; d = ei[1600000 + 2 * e]; }
  else     { s = ei[e];     d = ei[800000 + e]; }
  s = s < 0 ? 0 : (s > N_NODES - 1 ? N_NODES - 1 : s);
  d = d < 0 ? 0 : (d > N_NODES - 1 ? N_NODES - 1 : d);
  srcW[e] = s; dstW[e] = d;
}

__global__ __launch_bounds__(256) void k_hist(const int* __restrict__ dstW,
                                              int* __restrict__ cnt) {
  int e = blockIdx.x * 256 + threadIdx.x;
  if (e < N_EDGES) atomicAdd(&cnt[dstW[e]], 1);
}

__global__ __launch_bounds__(256) void k_scan1(const int* __restrict__ cnt,
                                               int* __restrict__ rp,
                                               int* __restrict__ bsum) {
  __shared__ int sd[256];
  int t = threadIdx.x;
  int i0 = blockIdx.x * 1024 + t * 4;
  int v0 = (i0 + 0) < N_NODES ? cnt[i0 + 0] : 0;
  int v1 = (i0 + 1) < N_NODES ? cnt[i0 + 1] : 0;
  int v2 = (i0 + 2) < N_NODES ? cnt[i0 + 2] : 0;
  int v3 = (i0 + 3) < N_NODES ? cnt[i0 + 3] : 0;
  int ts = v0 + v1 + v2 + v3;
  sd[t] = ts;
  __syncthreads();
  for (int off = 1; off < 256; off <<= 1) {
    int x = (t >= off) ? sd[t - off] : 0;
    __syncthreads();
    sd[t] += x;
    __syncthreads();
  }
  int exoff = sd[t] - ts;
  if (i0 + 0 < N_NODES) rp[i0 + 0] = exoff;
  if (i0 + 1 < N_NODES) rp[i0 + 1] = exoff + v0;
  if (i0 + 2 < N_NODES) rp[i0 + 2] = exoff + v0 + v1;
  if (i0 + 3 < N_NODES) rp[i0 + 3] = exoff + v0 + v1 + v2;
  if (t == 255) bsum[blockIdx.x] = sd[255];
}

__global__ void k_scan2(const int* __restrict__ bsum, int* __restrict__ boff,
                        int* __restrict__ rp, int nb) {
  if (threadIdx.x == 0) {
    int run = 0;
    for (int b = 0; b < nb; ++b) { boff[b] = run; run += bsum[b]; }
    rp[N_NODES] = run;
  }
}

__global__ __launch_bounds__(256) void k_scan3(int* __restrict__ rp,
                                               const int* __restrict__ boff,
                                               int* __restrict__ cursor) {
  int i = blockIdx.x * 256 + threadIdx.x;
  if (i < N_NODES) {
    int r = rp[i] + boff[i >> 10];
    rp[i] = r;
    cursor[i] = r;
  }
}

__global__ __launch_bounds__(256) void k_place(const int* __restrict__ srcW,
                                               const int* __restrict__ dstW,
                                               const void* ea, const int* __restrict__ flags,
                                               int* __restrict__ cursor,
                                               int* __restrict__ eSrc,
                                               float* __restrict__ eW) {
  int e = blockIdx.x * 256 + threadIdx.x;
  if (e >= N_EDGES) return;
  int d = dstW[e];
  int pos = atomicAdd(&cursor[d], 1);
  eSrc[pos] = srcW[e];
  eW[pos] = ldS(ea, flags[1], e);
}

__global__ __launch_bounds__(256) void k_degc(const int* __restrict__ rp,
                                              const float* __restrict__ eW,
                                              float* __restrict__ dinv) {
  const int i = blockIdx.x * 4 + (threadIdx.x >> 6);
  if (i >= N_NODES) return;
  const int lane = threadIdx.x & 63;
  const int base = rp[i], end = rp[i + 1];
  float s = 0.f;
  for (int j = base + lane; j < end; j += 64) s += eW[j];
#pragma unroll
  for (int off = 32; off > 0; off >>= 1) s += __shfl_xor(s, off, 64);
  if (lane == 0) dinv[i] = rsqrtf(s + 1.0f);
}

__global__ __launch_bounds__(256) void k_scale(const int* __restrict__ eSrc,
                                               const float* __restrict__ dinv,
                                               float* __restrict__ eW) {
  int j = blockIdx.x * 256 + threadIdx.x;
  if (j < N_EDGES) eW[j] *= dinv[eSrc[j]];
}

// Merged: blocks 0..287 transpose W1T/WgT; block 288 computes folded head vectors.
__global__ __launch_bounds__(512) void k_prep(
    const void* f1W, const void* g1W, const void* f2W, const void* f2b,
    const void* g2W, const void* g2b, const void* ffW, const void* ffb,
    const int* __restrict__ flags, unsigned short* __restrict__ W1T,
    unsigned short* __restrict__ WgT, float* __restrict__ w2f,
    float* __restrict__ w2g, float* __restrict__ constv) {
  const int fw = flags[3];
  if (blockIdx.x < 288) {
    int tid = blockIdx.x * 512 + threadIdx.x;
    if (tid < 512 * 256) {
      int c = tid >> 8, k = tid & 255;
      W1T[tid] = f2bf(ldS(f1W, fw, (size_t)k * 512 + c));
    } else if (tid < 512 * 256 + 64 * 256) {
      int j = tid - 512 * 256;
      int c = j >> 8, k = j & 255;
      WgT[j] = f2bf(ldS(g1W, fw, (size_t)k * 64 + c));
    }
    return;
  }
  int t = threadIdx.x;
  if (t < 512) {
    float s = 0.f;
    for (int c = 0; c < 64; ++c) s += ldS(f2W, fw, t * 64 + c) * ldS(ffW, fw, c);
    w2f[t] = s;
  }
  if (t < 64) {
    float s = 0.f;
    for (int c = 0; c < 64; ++c) s += ldS(g2W, fw, t * 64 + c) * ldS(ffW, fw, 64 + c);
    w2g[t] = s;
  }
  if (t == 0) {
    float s = ldS(ffb, fw, 0);
    for (int c = 0; c < 64; ++c) {
      s += ldS(f2b, fw, c) * ldS(ffW, fw, c);
      s += ldS(g2b, fw, c) * ldS(ffW, fw, 64 + c);
    }
    constv[0] = s;
  }
}

// ---------------------------------------------------------------------------
// h1b = x @ gcn1_W. Block = 64 nodes; B staged in LDS (shared by 4 waves);
// wave w owns c-tile [w*16, w*16+16) x 64 nodes (acc 16 AGPR).
// ---------------------------------------------------------------------------
template <int F32>
__global__ __launch_bounds__(256, 4) void k_h13(
    const void* x, const unsigned short* __restrict__ WgT,
    const int* __restrict__ flags, unsigned short* __restrict__ h1b) {
  if (flags[0] != F32) return;
  __shared__ unsigned short Bs[64 * BROW];
  const int nb = blockIdx.x * 64;
  stageB<F32>(x, nb, Bs);
  __syncthreads();

  const int lane = threadIdx.x & 63;
  const int wave = threadIdx.x >> 6;
  const int l15 = lane & 15;
  const int quad = lane >> 4;

  const unsigned short* ap = WgT + (size_t)(wave * 16 + l15) * 256 + quad * 8;

  f32x4 acc[4];
#pragma unroll
  for (int u = 0; u < 4; ++u) acc[u] = (f32x4){0.f, 0.f, 0.f, 0.f};

  bfrag8 aa[2];
  aa[0] = *(const bfrag8*)(ap);
#pragma unroll
  for (int ks = 0; ks < 8; ++ks) {
    const int cur = ks & 1;
    if (ks < 7) aa[cur ^ 1] = *(const bfrag8*)(ap + (ks + 1) * 32);
    const int bofs = ks * 32 + quad * 8;
#pragma unroll
    for (int u = 0; u < 4; ++u) {
      bfrag8 b = *(const bfrag8*)(Bs + (u * 16 + l15) * BROW + bofs);
      acc[u] = __builtin_amdgcn_mfma_f32_16x16x32_bf16(aa[cur], b, acc[u], 0, 0, 0);
    }
  }
#pragma unroll
  for (int u = 0; u < 4; ++u) {
    int node = nb + u * 16 + l15;
    if (node < N_NODES) {
      us4 o;
#pragma unroll
      for (int r = 0; r < 4; ++r) o[r] = f2bf(acc[u][r]);
      *(us4*)(h1b + (size_t)node * 64 + wave * 16 + quad * 4) = o;
    }
  }
}

// ---------------------------------------------------------------------------
// mlpc = folded MLP branch. Block = 64 nodes x all 512 c: B staged once in
// LDS, then two c-half passes; wave owns 64c x 64n per pass (acc 64 AGPR).
// ---------------------------------------------------------------------------
template <int F32>
__global__ __launch_bounds__(256, 3) void k_mlp3(
    const void* uf, const unsigned short* __restrict__ W1T,
    const void* fc1b, const float* __restrict__ w2f,
    const int* __restrict__ flags, float* __restrict__ mlpc) {
  if (flags[2] != F32) return;
  __shared__ unsigned short Bs[64 * BROW];
  const int nb = blockIdx.x * 64;
  stageB<F32>(uf, nb, Bs);
  __syncthreads();

  const int fw = flags[3];
  const int lane = threadIdx.x & 63;
  const int wave = threadIdx.x >> 6;
  const int l15 = lane & 15;
  const int quad = lane >> 4;

  int node[4];
#pragma unroll
  for (int u = 0; u < 4; ++u) node[u] = nb + u * 16 + l15;

  for (int half = 0; half < 2; ++half) {
    const int c_base = half * 256 + wave * 64;
    const unsigned short* ap[4];
#pragma unroll
    for (int t = 0; t < 4; ++t)
      ap[t] = W1T + (size_t)(c_base + t * 16 + l15) * 256 + quad * 8;

    f32x4 acc[4][4];
#pragma unroll
    for (int t = 0; t < 4; ++t)
#pragma unroll
      for (int u = 0; u < 4; ++u) acc[t][u] = (f32x4){0.f, 0.f, 0.f, 0.f};

    bfrag8 aa[2][4];
#pragma unroll
    for (int t = 0; t < 4; ++t) aa[0][t] = *(const bfrag8*)(ap[t]);

#pragma unroll
    for (int ks = 0; ks < 8; ++ks) {
      const int cur = ks & 1, nxt = cur ^ 1;
      if (ks < 7) {
        const int k1 = (ks + 1) * 32;
#pragma unroll
        for (int t = 0; t < 4; ++t) aa[nxt][t] = *(const bfrag8*)(ap[t] + k1);
      }
      const int bofs = ks * 32 + quad * 8;
      bfrag8 b[4];
#pragma unroll
      for (int u = 0; u < 4; ++u)
        b[u] = *(const bfrag8*)(Bs + (u * 16 + l15) * BROW + bofs);
#pragma unroll
      for (int t = 0; t < 4; ++t)
#pragma unroll
        for (int u = 0; u < 4; ++u)
          acc[t][u] = __builtin_amdgcn_mfma_f32_16x16x32_bf16(aa[cur][t], b[u], acc[t][u], 0, 0, 0);
    }

    float part[4] = {0.f, 0.f, 0.f, 0.f};
#pragma unroll
    for (int t = 0; t < 4; ++t) {
#pragma unroll
      for (int r = 0; r < 4; ++r) {
        const int c = c_base + t * 16 + quad * 4 + r;
        const float bc = ldS(fc1b, fw, c);
        const float wc = w2f[c];
#pragma unroll
        for (int u = 0; u < 4; ++u) {
          float v = acc[t][u][r] + bc;
          v = v > 0.f ? v : 0.f;
          part[u] += v * wc;
        }
      }
    }
#pragma unroll
    for (int u = 0; u < 4; ++u) {
      part[u] += __shfl_xor(part[u], 16, 64);
      part[u] += __shfl_xor(part[u], 32, 64);
      if (lane < 16 && node[u] < N_NODES) atomicAdd(&mlpc[node[u]], part[u]);
    }
  }
}

// Fused layer-1 aggregation + layer-2 input projection (8-edge unroll).
__global__ __launch_bounds__(256) void k_aggs2(
    const int* __restrict__ rp, const int* __restrict__ eSrc,
    const float* __restrict__ eW, const unsigned short* __restrict__ h1b,
    const float* __restrict__ dinv, const void* g1b, const float* __restrict__ w2g,
    const int* __restrict__ flags, float* __restrict__ s2) {
  const int i = blockIdx.x * 4 + (threadIdx.x >> 6);
  if (i >= N_NODES) return;
  const int lane = threadIdx.x & 63;
  const int base = rp[i], end = rp[i + 1];
  const float di = dinv[i];
  float acc = 0.f;
  int j = base;
  for (; j + 8 <= end; j += 8) {
    int ss[8]; float ww[8];
#pragma unroll
    for (int q = 0; q < 8; ++q) { ss[q] = eSrc[j + q]; ww[q] = eW[j + q]; }
    float hv[8];
#pragma unroll
    for (int q = 0; q < 8; ++q) hv[q] = bf2f(h1b[(size_t)ss[q] * 64 + lane]);
#pragma unroll
    for (int q = 0; q < 8; ++q) acc += ww[q] * hv[q];
  }
  for (; j < end; ++j) acc += eW[j] * bf2f(h1b[(size_t)eSrc[j] * 64 + lane]);
  float v = acc * di + di * di * bf2f(h1b[(size_t)i * 64 + lane]) + ldS(g1b, flags[3], lane);
  v = v > 0.f ? v : 0.f;
  float p = v * w2g[lane];
#pragma unroll
  for (int off = 32; off > 0; off >>= 1) p += __shfl_xor(p, off, 64);
  if (lane == 0) s2[i] = p;
}

// Fused layer-2 aggregation + final output.
__global__ __launch_bounds__(256) void k_fin2(
    const int* __restrict__ rp, const int* __restrict__ eSrc,
    const float* __restrict__ eW, const float* __restrict__ s2,
    const float* __restrict__ dinv, const float* __restrict__ mlpc,
    const float* __restrict__ constv, const int* __restrict__ flags, void* out) {
  const int i = blockIdx.x * 4 + (threadIdx.x >> 6);
  if (i >= N_NODES) return;
  const int lane = threadIdx.x & 63;
  const int base = rp[i], end = rp[i + 1];
  float p = 0.f;
  for (int j = base + lane; j < end; j += 64) p += eW[j] * s2[eSrc[j]];
#pragma unroll
  for (int off = 32; off > 0; off >>= 1) p += __shfl_xor(p, off, 64);
  if (lane == 0) {
    float di = dinv[i];
    stO(out, flags[5], i, mlpc[i] + di * p + di * di * s2[i] + constv[0]);
  }
}

__global__ __launch_bounds__(256) void k_zero(const int* __restrict__ flags, void* out) {
  int i = blockIdx.x * 256 + threadIdx.x;
  if (i < N_NODES) stO(out, flags[5], i, 0.f);
}

extern "C" void kernel_launch(void* const* d_in, const int* in_sizes, int n_in,
                              void* d_out, int out_size, void* d_ws, size_t ws_size,
                              hipStream_t stream) {
  const void* x   = d_in[0];
  const int*  ei  = (const int*)d_in[1];
  const void* ea  = d_in[2];
  const void* uf  = d_in[3];
  const void* g1W = d_in[4];
  const void* g1b = d_in[5];
  const void* g2W = d_in[6];
  const void* g2b = d_in[7];
  const void* f1W = d_in[8];
  const void* f1b = d_in[9];
  const void* f2W = d_in[10];
  const void* f2b = d_in[11];
  const void* ffW = d_in[12];
  const void* ffb = d_in[13];

  float* ws = (float*)d_ws;
  int*   flags  = (int*)ws;                 // 16
  float* w2f    = ws + 16;                  // 512
  float* w2g    = ws + 528;                 // 64
  float* constv = ws + 592;                 // 16
  float* dinv   = ws + 608;                 // 50,000
  float* s2     = ws + 50608;               // 50,000
  float* mlpc   = ws + 100608;              // 50,000
  unsigned short* W1T = (unsigned short*)(ws + 150608);  // 131,072 us
  unsigned short* WgT = W1T + 131072;                    // 16,384 us
  int* srcW   = (int*)(ws + 224336);        // 800,000
  int* dstW   = srcW + 800000;              // 800,000
  int* rowptr = dstW + 800000;              // 50,001 (pad 16)
  int* bsum   = (int*)(ws + 1874352);       // 64
  int* boff   = bsum + 64;                  // 64
  int* counts = (int*)(ws + 1874480);       // 50,016
  int* cursor = (int*)(ws + 1924496);       // 50,000
  int* eSrc   = (int*)(ws + 1974496);       // 800,000
  float* eW   = ws + 2774496;               // 800,000
  unsigned short* h1b = (unsigned short*)(ws + 3574496); // 3.2M us
  const size_t NEED = (size_t)5174496 * 4;  // ~20.7 MB

  k_detect<<<1, 64, 0, stream>>>(x, ea, uf, f1W, ei, flags);
  if (ws_size < NEED) {
    k_zero<<<(N_NODES + 255) / 256, 256, 0, stream>>>(flags, d_out);
    return;
  }
  const int NB = (N_NODES + 1023) / 1024;   // 49
  const int NGB = (N_NODES + 63) / 64;      // 782

  k_edges<<<(N_EDGES + 255) / 256, 256, 0, stream>>>(ei, flags, srcW, dstW, counts, mlpc);
  k_hist<<<(N_EDGES + 255) / 256, 256, 0, stream>>>(dstW, counts);
  k_scan1<<<NB, 256, 0, stream>>>(counts, rowptr, bsum);
  k_scan2<<<1, 64, 0, stream>>>(bsum, boff, rowptr, NB);
  k_scan3<<<(N_NODES + 255) / 256, 256, 0, stream>>>(rowptr, boff, cursor);
  k_place<<<(N_EDGES + 255) / 256, 256, 0, stream>>>(srcW, dstW, ea, flags, cursor, eSrc, eW);
  k_degc<<<(N_NODES + 3) / 4, 256, 0, stream>>>(rowptr, eW, dinv);
  k_scale<<<(N_EDGES + 255) / 256, 256, 0, stream>>>(eSrc, dinv, eW);
  k_prep<<<289, 512, 0, stream>>>(f1W, g1W, f2W, f2b, g2W, g2b, ffW, ffb, flags,
                                  W1T, WgT, w2f, w2g, constv);
  k_h13<0><<<NGB, 256, 0, stream>>>(x, WgT, flags, h1b);
  k_h13<1><<<NGB, 256, 0, stream>>>(x, WgT, flags, h1b);
  k_mlp3<0><<<NGB, 256, 0, stream>>>(uf, W1T, f1b, w2f, flags, mlpc);
  k_mlp3<1><<<NGB, 256, 0, stream>>>(uf, W1T, f1b, w2f, flags, mlpc);
  k_aggs2<<<(N_NODES + 3) / 4, 256, 0, stream>>>(rowptr, eSrc, eW, h1b, dinv, g1b, w2g, flags, s2);
  k_fin2<<<(N_NODES + 3) / 4, 256, 0, stream>>>(rowptr, eSrc, eW, s2, dinv, mlpc, constv, flags, d_out);
}

// Round 8
// 402.277 us; speedup vs baseline: 1.0989x; 1.0989x over previous
//
#include <hip/hip_runtime.h>
#include <hip/hip_bf16.h>

#define N_NODES 50000
#define N_EDGES 800000
#define BROW 264   // padded LDS row stride in us (528 B = 33*16 -> b128-aligned)

typedef __attribute__((ext_vector_type(8))) short bfrag8;   // 8 bf16 (4 VGPRs)
typedef __attribute__((ext_vector_type(4))) float f32x4;
typedef __attribute__((ext_vector_type(4))) unsigned short us4;
typedef __attribute__((ext_vector_type(8))) unsigned short us8;

__device__ __forceinline__ float bf2f(unsigned short u) {
  return __uint_as_float(((unsigned int)u) << 16);
}
__device__ __forceinline__ unsigned short f2bf(float f) {
  unsigned int u = __float_as_uint(f);
  u = (u + 0x7fffu + ((u >> 16) & 1u)) >> 16;
  return (unsigned short)u;
}
__device__ __forceinline__ float ldS(const void* p, int f32, size_t i) {
  return f32 ? ((const float*)p)[i] : bf2f(((const unsigned short*)p)[i]);
}
__device__ __forceinline__ void stO(void* out, int f32, int i, float v) {
  if (f32) ((float*)out)[i] = v;
  else ((unsigned short*)out)[i] = f2bf(v);
}

// Stage 64 rows x 256 cols of src into LDS as bf16.
// 256 threads: thread t -> row t>>2, quarter t&3 (64 elems).
template <int F32>
__device__ __forceinline__ void stageB(const void* src, int nb,
                                       unsigned short* __restrict__ Bs) {
  const int t = threadIdx.x;
  const int r = t >> 2;
  const int q = t & 3;
  int row = nb + r;
  row = row < N_NODES ? row : (N_NODES - 1);
  const size_t base = (size_t)row * 256 + q * 64;
  unsigned short* dst = Bs + r * BROW + q * 64;
  if (F32) {
    const f32x4* s4 = (const f32x4*)((const float*)src + base);
#pragma unroll
    for (int j = 0; j < 8; ++j) {
      f32x4 a = s4[2 * j], b = s4[2 * j + 1];
      us8 o;
      o[0] = f2bf(a[0]); o[1] = f2bf(a[1]); o[2] = f2bf(a[2]); o[3] = f2bf(a[3]);
      o[4] = f2bf(b[0]); o[5] = f2bf(b[1]); o[6] = f2bf(b[2]); o[7] = f2bf(b[3]);
      *(us8*)(dst + j * 8) = o;
    }
  } else {
    const us8* s8 = (const us8*)((const unsigned short*)src + base);
#pragma unroll
    for (int j = 0; j < 8; ++j) *(us8*)(dst + j * 8) = s8[j];
  }
}

// flags: 0=x_is_f32 1=ea_is_f32 2=uf_is_f32 3=W_is_f32 4=idx_is_i64 5=out_is_f32
__global__ void k_detect(const void* x, const void* ea, const void* uf,
                         const void* f1W, const int* ei, int* flags) {
  int lane = threadIdx.x & 63;
  unsigned short ux = ((const unsigned short*)x)[lane];
  unsigned short ue = ((const unsigned short*)ea)[lane];
  unsigned short uu = ((const unsigned short*)uf)[lane];
  unsigned short uw = ((const unsigned short*)f1W)[lane];
  int oi = ei[2 * lane + 1];
  unsigned long long bx = __ballot(((ux >> 7) & 0xFF) > 0x85);
  unsigned long long be = __ballot((ue & 0x8000u) != 0);
  unsigned long long bu = __ballot(((uu >> 7) & 0xFF) > 0x85);
  unsigned long long bw = __ballot(((uw >> 7) & 0xFF) > 0x7E);
  unsigned long long bi = __ballot(oi != 0);
  if (lane == 0) {
    int fx = bx ? 1 : 0, fe = be ? 1 : 0, fu = bu ? 1 : 0, fw = bw ? 1 : 0;
    flags[0] = fx; flags[1] = fe; flags[2] = fu; flags[3] = fw;
    flags[4] = (bi == 0ull) ? 1 : 0;
    flags[5] = (fx & fe & fu & fw);
  }
}

// Normalize edges + zero counts/mlpc (one pass over 800k).
__global__ __launch_bounds__(256) void k_edges(const int* __restrict__ ei,
                                               const int* __restrict__ flags,
                                               int* __restrict__ srcW,
                                               int* __restrict__ dstW,
                                               int* __restrict__ cnt,
                                               float* __restrict__ mlpc) {
  int e = blockIdx.x * 256 + threadIdx.x;
  if (e >= N_EDGES) return;
  if (e <= N_NODES) cnt[e] = 0;
  if (e < N_NODES) mlpc[e] = 0.f;
  int i64 = flags[4];
  int s, d;
  if (i64) { s = ei[2 * e]; d = ei[1600000 + 2 * e]; }
  else     { s = ei[e];     d = ei[800000 + e]; }
  s = s < 0 ? 0 : (s > N_NODES - 1 ? N_NODES - 1 : s);
  d = d < 0 ? 0 : (d > N_NODES - 1 ? N_NODES - 1 : d);
  srcW[e] = s; dstW[e] = d;
}

__global__ __launch_bounds__(256) void k_hist(const int* __restrict__ dstW,
                                              int* __restrict__ cnt) {
  int e = blockIdx.x * 256 + threadIdx.x;
  if (e < N_EDGES) atomicAdd(&cnt[dstW[e]], 1);
}

__global__ __launch_bounds__(256) void k_scan1(const int* __restrict__ cnt,
                                               int* __restrict__ rp,
                                               int* __restrict__ bsum) {
  __shared__ int sd[256];
  int t = threadIdx.x;
  int i0 = blockIdx.x * 1024 + t * 4;
  int v0 = (i0 + 0) < N_NODES ? cnt[i0 + 0] : 0;
  int v1 = (i0 + 1) < N_NODES ? cnt[i0 + 1] : 0;
  int v2 = (i0 + 2) < N_NODES ? cnt[i0 + 2] : 0;
  int v3 = (i0 + 3) < N_NODES ? cnt[i0 + 3] : 0;
  int ts = v0 + v1 + v2 + v3;
  sd[t] = ts;
  __syncthreads();
  for (int off = 1; off < 256; off <<= 1) {
    int x = (t >= off) ? sd[t - off] : 0;
    __syncthreads();
    sd[t] += x;
    __syncthreads();
  }
  int exoff = sd[t] - ts;
  if (i0 + 0 < N_NODES) rp[i0 + 0] = exoff;
  if (i0 + 1 < N_NODES) rp[i0 + 1] = exoff + v0;
  if (i0 + 2 < N_NODES) rp[i0 + 2] = exoff + v0 + v1;
  if (i0 + 3 < N_NODES) rp[i0 + 3] = exoff + v0 + v1 + v2;
  if (t == 255) bsum[blockIdx.x] = sd[255];
}

__global__ void k_scan2(const int* __restrict__ bsum, int* __restrict__ boff,
                        int* __restrict__ rp, int nb) {
  if (threadIdx.x == 0) {
    int run = 0;
    for (int b = 0; b < nb; ++b) { boff[b] = run; run += bsum[b]; }
    rp[N_NODES] = run;
  }
}

__global__ __launch_bounds__(256) void k_scan3(int* __restrict__ rp,
                                               const int* __restrict__ boff,
                                               int* __restrict__ cursor) {
  int i = blockIdx.x * 256 + threadIdx.x;
  if (i < N_NODES) {
    int r = rp[i] + boff[i >> 10];
    rp[i] = r;
    cursor[i] = r;
  }
}

__global__ __launch_bounds__(256) void k_place(const int* __restrict__ srcW,
                                               const int* __restrict__ dstW,
                                               const void* ea, const int* __restrict__ flags,
                                               int* __restrict__ cursor,
                                               int* __restrict__ eSrc,
                                               float* __restrict__ eW) {
  int e = blockIdx.x * 256 + threadIdx.x;
  if (e >= N_EDGES) return;
  int d = dstW[e];
  int pos = atomicAdd(&cursor[d], 1);
  eSrc[pos] = srcW[e];
  eW[pos] = ldS(ea, flags[1], e);
}

__global__ __launch_bounds__(256) void k_degc(const int* __restrict__ rp,
                                              const float* __restrict__ eW,
                                              float* __restrict__ dinv) {
  const int i = blockIdx.x * 4 + (threadIdx.x >> 6);
  if (i >= N_NODES) return;
  const int lane = threadIdx.x & 63;
  const int base = rp[i], end = rp[i + 1];
  float s = 0.f;
  for (int j = base + lane; j < end; j += 64) s += eW[j];
#pragma unroll
  for (int off = 32; off > 0; off >>= 1) s += __shfl_xor(s, off, 64);
  if (lane == 0) dinv[i] = rsqrtf(s + 1.0f);
}

__global__ __launch_bounds__(256) void k_scale(const int* __restrict__ eSrc,
                                               const float* __restrict__ dinv,
                                               float* __restrict__ eW) {
  int j = blockIdx.x * 256 + threadIdx.x;
  if (j < N_EDGES) eW[j] *= dinv[eSrc[j]];
}

// Merged: blocks 0..287 transpose W1T/WgT; block 288 computes folded head vectors.
__global__ __launch_bounds__(512) void k_prep(
    const void* f1W, const void* g1W, const void* f2W, const void* f2b,
    const void* g2W, const void* g2b, const void* ffW, const void* ffb,
    const int* __restrict__ flags, unsigned short* __restrict__ W1T,
    unsigned short* __restrict__ WgT, float* __restrict__ w2f,
    float* __restrict__ w2g, float* __restrict__ constv) {
  const int fw = flags[3];
  if (blockIdx.x < 288) {
    int tid = blockIdx.x * 512 + threadIdx.x;
    if (tid < 512 * 256) {
      int c = tid >> 8, k = tid & 255;
      W1T[tid] = f2bf(ldS(f1W, fw, (size_t)k * 512 + c));
    } else if (tid < 512 * 256 + 64 * 256) {
      int j = tid - 512 * 256;
      int c = j >> 8, k = j & 255;
      WgT[j] = f2bf(ldS(g1W, fw, (size_t)k * 64 + c));
    }
    return;
  }
  int t = threadIdx.x;
  if (t < 512) {
    float s = 0.f;
    for (int c = 0; c < 64; ++c) s += ldS(f2W, fw, t * 64 + c) * ldS(ffW, fw, c);
    w2f[t] = s;
  }
  if (t < 64) {
    float s = 0.f;
    for (int c = 0; c < 64; ++c) s += ldS(g2W, fw, t * 64 + c) * ldS(ffW, fw, 64 + c);
    w2g[t] = s;
  }
  if (t == 0) {
    float s = ldS(ffb, fw, 0);
    for (int c = 0; c < 64; ++c) {
      s += ldS(f2b, fw, c) * ldS(ffW, fw, c);
      s += ldS(g2b, fw, c) * ldS(ffW, fw, 64 + c);
    }
    constv[0] = s;
  }
}

// ---------------------------------------------------------------------------
// h1b = x @ gcn1_W. Block = 64 nodes; B staged in LDS (shared by 4 waves);
// wave w owns c-tile [w*16,+16) x 64 nodes (acc 16 regs). No A-dbuf.
// ---------------------------------------------------------------------------
template <int F32>
__global__ __launch_bounds__(256, 3) void k_h13(
    const void* x, const unsigned short* __restrict__ WgT,
    const int* __restrict__ flags, unsigned short* __restrict__ h1b) {
  if (flags[0] != F32) return;
  __shared__ unsigned short Bs[64 * BROW];
  const int nb = blockIdx.x * 64;
  stageB<F32>(x, nb, Bs);
  __syncthreads();

  const int lane = threadIdx.x & 63;
  const int wave = threadIdx.x >> 6;
  const int l15 = lane & 15;
  const int quad = lane >> 4;
  const unsigned short* ap = WgT + (size_t)(wave * 16 + l15) * 256 + quad * 8;

  f32x4 acc[4];
#pragma unroll
  for (int u = 0; u < 4; ++u) acc[u] = (f32x4){0.f, 0.f, 0.f, 0.f};

#pragma unroll
  for (int ks = 0; ks < 8; ++ks) {
    bfrag8 a = *(const bfrag8*)(ap + ks * 32);
    const int bofs = ks * 32 + quad * 8;
#pragma unroll
    for (int u = 0; u < 4; ++u) {
      bfrag8 b = *(const bfrag8*)(Bs + (u * 16 + l15) * BROW + bofs);
      acc[u] = __builtin_amdgcn_mfma_f32_16x16x32_bf16(a, b, acc[u], 0, 0, 0);
    }
  }
#pragma unroll
  for (int u = 0; u < 4; ++u) {
    int node = nb + u * 16 + l15;
    if (node < N_NODES) {
      us4 o;
#pragma unroll
      for (int r = 0; r < 4; ++r) o[r] = f2bf(acc[u][r]);
      *(us4*)(h1b + (size_t)node * 64 + wave * 16 + quad * 4) = o;
    }
  }
}

// ---------------------------------------------------------------------------
// mlpc = folded MLP branch. Block = 64 nodes x 512 c: B staged once in LDS,
// two c-half passes; wave owns 64c x 64n per pass (acc 64 regs).
// __launch_bounds__(256,2): 256-reg budget -> no scratch spill (R7's 93-µs bug).
// ---------------------------------------------------------------------------
template <int F32>
__global__ __launch_bounds__(256, 2) void k_mlp4(
    const void* uf, const unsigned short* __restrict__ W1T,
    const void* fc1b, const float* __restrict__ w2f,
    const int* __restrict__ flags, float* __restrict__ mlpc) {
  if (flags[2] != F32) return;
  __shared__ unsigned short Bs[64 * BROW];
  const int nb = blockIdx.x * 64;
  stageB<F32>(uf, nb, Bs);
  __syncthreads();

  const int fw = flags[3];
  const int lane = threadIdx.x & 63;
  const int wave = threadIdx.x >> 6;
  const int l15 = lane & 15;
  const int quad = lane >> 4;

  for (int half = 0; half < 2; ++half) {
    const int c_base = half * 256 + wave * 64;
    const unsigned short* ap = W1T + (size_t)(c_base + l15) * 256 + quad * 8;

    f32x4 acc[4][4];
#pragma unroll
    for (int t = 0; t < 4; ++t)
#pragma unroll
      for (int u = 0; u < 4; ++u) acc[t][u] = (f32x4){0.f, 0.f, 0.f, 0.f};

#pragma unroll
    for (int ks = 0; ks < 8; ++ks) {
      const int bofs = ks * 32 + quad * 8;
      bfrag8 b[4];
#pragma unroll
      for (int u = 0; u < 4; ++u)
        b[u] = *(const bfrag8*)(Bs + (u * 16 + l15) * BROW + bofs);
#pragma unroll
      for (int t = 0; t < 4; ++t) {
        bfrag8 a = *(const bfrag8*)(ap + (size_t)t * 16 * 256 + ks * 32);
#pragma unroll
        for (int u = 0; u < 4; ++u)
          acc[t][u] = __builtin_amdgcn_mfma_f32_16x16x32_bf16(a, b[u], acc[t][u], 0, 0, 0);
      }
    }

    float part[4] = {0.f, 0.f, 0.f, 0.f};
#pragma unroll
    for (int t = 0; t < 4; ++t) {
#pragma unroll
      for (int r = 0; r < 4; ++r) {
        const int c = c_base + t * 16 + quad * 4 + r;
        const float bc = ldS(fc1b, fw, c);
        const float wc = w2f[c];
#pragma unroll
        for (int u = 0; u < 4; ++u) {
          float v = acc[t][u][r] + bc;
          v = v > 0.f ? v : 0.f;
          part[u] += v * wc;
        }
      }
    }
#pragma unroll
    for (int u = 0; u < 4; ++u) {
      part[u] += __shfl_xor(part[u], 16, 64);
      part[u] += __shfl_xor(part[u], 32, 64);
      int node = nb + u * 16 + l15;
      if (lane < 16 && node < N_NODES) atomicAdd(&mlpc[node], part[u]);
    }
  }
}

// Fused layer-1 aggregation + layer-2 input projection (8-edge unroll).
__global__ __launch_bounds__(256) void k_aggs2(
    const int* __restrict__ rp, const int* __restrict__ eSrc,
    const float* __restrict__ eW, const unsigned short* __restrict__ h1b,
    const float* __restrict__ dinv, const void* g1b, const float* __restrict__ w2g,
    const int* __restrict__ flags, float* __restrict__ s2) {
  const int i = blockIdx.x * 4 + (threadIdx.x >> 6);
  if (i >= N_NODES) return;
  const int lane = threadIdx.x & 63;
  const int base = rp[i], end = rp[i + 1];
  const float di = dinv[i];
  float acc = 0.f;
  int j = base;
  for (; j + 8 <= end; j += 8) {
    int ss[8]; float ww[8];
#pragma unroll
    for (int q = 0; q < 8; ++q) { ss[q] = eSrc[j + q]; ww[q] = eW[j + q]; }
    float hv[8];
#pragma unroll
    for (int q = 0; q < 8; ++q) hv[q] = bf2f(h1b[(size_t)ss[q] * 64 + lane]);
#pragma unroll
    for (int q = 0; q < 8; ++q) acc += ww[q] * hv[q];
  }
  for (; j < end; ++j) acc += eW[j] * bf2f(h1b[(size_t)eSrc[j] * 64 + lane]);
  float v = acc * di + di * di * bf2f(h1b[(size_t)i * 64 + lane]) + ldS(g1b, flags[3], lane);
  v = v > 0.f ? v : 0.f;
  float p = v * w2g[lane];
#pragma unroll
  for (int off = 32; off > 0; off >>= 1) p += __shfl_xor(p, off, 64);
  if (lane == 0) s2[i] = p;
}

// Fused layer-2 aggregation + final output.
__global__ __launch_bounds__(256) void k_fin2(
    const int* __restrict__ rp, const int* __restrict__ eSrc,
    const float* __restrict__ eW, const float* __restrict__ s2,
    const float* __restrict__ dinv, const float* __restrict__ mlpc,
    const float* __restrict__ constv, const int* __restrict__ flags, void* out) {
  const int i = blockIdx.x * 4 + (threadIdx.x >> 6);
  if (i >= N_NODES) return;
  const int lane = threadIdx.x & 63;
  const int base = rp[i], end = rp[i + 1];
  float p = 0.f;
  for (int j = base + lane; j < end; j += 64) p += eW[j] * s2[eSrc[j]];
#pragma unroll
  for (int off = 32; off > 0; off >>= 1) p += __shfl_xor(p, off, 64);
  if (lane == 0) {
    float di = dinv[i];
    stO(out, flags[5], i, mlpc[i] + di * p + di * di * s2[i] + constv[0]);
  }
}

__global__ __launch_bounds__(256) void k_zero(const int* __restrict__ flags, void* out) {
  int i = blockIdx.x * 256 + threadIdx.x;
  if (i < N_NODES) stO(out, flags[5], i, 0.f);
}

extern "C" void kernel_launch(void* const* d_in, const int* in_sizes, int n_in,
                              void* d_out, int out_size, void* d_ws, size_t ws_size,
                              hipStream_t stream) {
  const void* x   = d_in[0];
  const int*  ei  = (const int*)d_in[1];
  const void* ea  = d_in[2];
  const void* uf  = d_in[3];
  const void* g1W = d_in[4];
  const void* g1b = d_in[5];
  const void* g2W = d_in[6];
  const void* g2b = d_in[7];
  const void* f1W = d_in[8];
  const void* f1b = d_in[9];
  const void* f2W = d_in[10];
  const void* f2b = d_in[11];
  const void* ffW = d_in[12];
  const void* ffb = d_in[13];

  float* ws = (float*)d_ws;
  int*   flags  = (int*)ws;                 // 16
  float* w2f    = ws + 16;                  // 512
  float* w2g    = ws + 528;                 // 64
  float* constv = ws + 592;                 // 16
  float* dinv   = ws + 608;                 // 50,000
  float* s2     = ws + 50608;               // 50,000
  float* mlpc   = ws + 100608;              // 50,000
  unsigned short* W1T = (unsigned short*)(ws + 150608);  // 131,072 us
  unsigned short* WgT = W1T + 131072;                    // 16,384 us
  int* srcW   = (int*)(ws + 224336);        // 800,000
  int* dstW   = srcW + 800000;              // 800,000
  int* rowptr = dstW + 800000;              // 50,001 (pad 16)
  int* bsum   = (int*)(ws + 1874352);       // 64
  int* boff   = bsum + 64;                  // 64
  int* counts = (int*)(ws + 1874480);       // 50,016
  int* cursor = (int*)(ws + 1924496);       // 50,000
  int* eSrc   = (int*)(ws + 1974496);       // 800,000
  float* eW   = ws + 2774496;               // 800,000
  unsigned short* h1b = (unsigned short*)(ws + 3574496); // 3.2M us
  const size_t NEED = (size_t)5174496 * 4;  // ~20.7 MB

  k_detect<<<1, 64, 0, stream>>>(x, ea, uf, f1W, ei, flags);
  if (ws_size < NEED) {
    k_zero<<<(N_NODES + 255) / 256, 256, 0, stream>>>(flags, d_out);
    return;
  }
  const int NB = (N_NODES + 1023) / 1024;   // 49
  const int NGB = (N_NODES + 63) / 64;      // 782

  k_edges<<<(N_EDGES + 255) / 256, 256, 0, stream>>>(ei, flags, srcW, dstW, counts, mlpc);
  k_hist<<<(N_EDGES + 255) / 256, 256, 0, stream>>>(dstW, counts);
  k_scan1<<<NB, 256, 0, stream>>>(counts, rowptr, bsum);
  k_scan2<<<1, 64, 0, stream>>>(bsum, boff, rowptr, NB);
  k_scan3<<<(N_NODES + 255) / 256, 256, 0, stream>>>(rowptr, boff, cursor);
  k_place<<<(N_EDGES + 255) / 256, 256, 0, stream>>>(srcW, dstW, ea, flags, cursor, eSrc, eW);
  k_degc<<<(N_NODES + 3) / 4, 256, 0, stream>>>(rowptr, eW, dinv);
  k_scale<<<(N_EDGES + 255) / 256, 256, 0, stream>>>(eSrc, dinv, eW);
  k_prep<<<289, 512, 0, stream>>>(f1W, g1W, f2W, f2b, g2W, g2b, ffW, ffb, flags,
                                  W1T, WgT, w2f, w2g, constv);
  k_h13<0><<<NGB, 256, 0, stream>>>(x, WgT, flags, h1b);
  k_h13<1><<<NGB, 256, 0, stream>>>(x, WgT, flags, h1b);
  k_mlp4<0><<<NGB, 256, 0, stream>>>(uf, W1T, f1b, w2f, flags, mlpc);
  k_mlp4<1><<<NGB, 256, 0, stream>>>(uf, W1T, f1b, w2f, flags, mlpc);
  k_aggs2<<<(N_NODES + 3) / 4, 256, 0, stream>>>(rowptr, eSrc, eW, h1b, dinv, g1b, w2g, flags, s2);
  k_fin2<<<(N_NODES + 3) / 4, 256, 0, stream>>>(rowptr, eSrc, eW, s2, dinv, mlpc, constv, flags, d_out);
}